// Round 15
// baseline (314.945 us; speedup 1.0000x reference)
//
#include <hip/hip_runtime.h>
#include <hip/hip_bf16.h>
#include <math.h>

#define N 1026
#define T 8
#define H 64
#define F_IN 5
#define E 1026
#define NNZ 200000
#define TM 7
#define NG 9
#define KP 1056        // padded rows/cols for conv GEMMs (66 * 16)
#define NWB 132        // nibble words per row (1056/8)
#define RT 96          // scan: rows per LDS tile
#define NT 11          // 11*96 = 1056 exactly
#define PB 4           // scan: edge-list portions (splits per-block scan bytes)
#define NH (N*H)
#define BZC 32         // bz chunk count
#define CHUNK (NH/BZC) // 2052

#define OFF_PRICE   0
#define OFF_WIH     41040
#define OFF_WHH     42000
#define OFF_BIH     54288
#define OFF_BHH     54480
#define OFF_WIN     54672
#define OFF_WOUT    58768
#define OFF_AE      66960
#define OFF_AB      67986
#define OFF_TH1     69012
#define OFF_B1      73108
#define OFF_TH2     73172
#define OFF_B2      77268
#define OFF_W1      77332
#define OFF_W2      77780
#define OFF_APAR    78228
#define OFF_WL      78235
#define OFF_BL      78363
#define TOT_CVT     78364

typedef unsigned int u32;
typedef unsigned short u16;
typedef short bf16x8 __attribute__((ext_vector_type(8)));
typedef float f32x4 __attribute__((ext_vector_type(4)));

__device__ __forceinline__ float leakyf(float x){ return x >= 0.f ? x : 0.2f*x; }
__device__ __forceinline__ float bfbits2f(u16 u){
  union { u32 i; float f; } c; c.i = ((u32)u) << 16; return c.f;
}
__device__ __forceinline__ u16 f2bf(float f){      // round-to-nearest-even
  u32 x = __builtin_bit_cast(u32, f);
  u32 r = x + 0x7FFFu + ((x >> 16) & 1u);
  return (u16)(r >> 16);
}
__device__ __forceinline__ int detect_f32(const u16* __restrict__ w){
  int lane = threadIdx.x & 63;
  int big = 0;
  for (int k = lane; k < 960; k += 64){
    float a = fabsf(bfbits2f(w[k]));
    if (!(a < 1e3f)) big = 1;
  }
  return (__ballot(big != 0) != 0ull) ? 1 : 0;
}

struct CvtPtrs { const void* p[18]; };

__global__ __launch_bounds__(256) void k_cvt(CvtPtrs ps, float* __restrict__ dst){
  const int offs[19] = {OFF_PRICE, OFF_WIH, OFF_WHH, OFF_BIH, OFF_BHH, OFF_WIN,
                        OFF_WOUT, OFF_AE, OFF_AB, OFF_TH1, OFF_B1, OFF_TH2,
                        OFF_B2, OFF_W1, OFF_W2, OFF_APAR, OFF_WL, OFF_BL, TOT_CVT};
  int isf32 = detect_f32((const u16*)ps.p[1]);
  int i = blockIdx.x*256 + threadIdx.x;
  if (i < TOT_CVT){
    int t = 0;
    #pragma unroll
    for (int k = 1; k < 18; k++) if (i >= offs[k]) t = k;
    int j = i - offs[t];
    float v;
    if (isf32) v = ((const float*)ps.p[t])[j];
    else       v = bfbits2f(((const u16*)ps.p[t])[j]);
    dst[i] = v;
  }
}

// Scan phase: grid (NT*PB, NG, 2), 256 thr, 3 blocks/CU. Each block scans
// NNZ/PB edges into an LDS nibble tile, then flushes NONZERO words with
// coalesced global atomicAdd into the u32 nibble matrix. (R14's monolithic
// build: 45 us — per-block time = full 1.6 MB edge stream through one CU.)
__global__ __launch_bounds__(256) void k_scan(const int* __restrict__ hypT,
                                              const int* __restrict__ hyp,
                                              u32* __restrict__ nHm,
                                              u32* __restrict__ nHmT){
  __shared__ u32 bins[RT*NWB];          // 50,688 B
  int tid = threadIdx.x;
  int tile = blockIdx.x / PB, prt = blockIdx.x - tile*PB;
  int g = blockIdx.y, side = blockIdx.z;
  int r0 = tile * RT;
  for (int k = tid; k < RT*NWB; k += 256) bins[k] = 0;
  __syncthreads();
  const int4* np4; const int4* ep4;
  if (g < 8){ const int* np_ = hypT + (size_t)g*2*NNZ;
              np4 = (const int4*)np_; ep4 = (const int4*)(np_ + NNZ); }
  else      { np4 = (const int4*)hyp; ep4 = (const int4*)(hyp + NNZ); }
  int i0 = prt * (NNZ/4/PB);            // 12500 int4-groups per portion
  int i1 = i0 + (NNZ/4/PB);
  #pragma unroll 2
  for (int i = i0 + tid; i < i1; i += 256){
    int4 a4 = np4[i], b4 = ep4[i];
    int ra[4], ca[4];
    if (side){
      ra[0]=b4.x; ra[1]=b4.y; ra[2]=b4.z; ra[3]=b4.w;
      ca[0]=a4.x; ca[1]=a4.y; ca[2]=a4.z; ca[3]=a4.w;
    } else {
      ra[0]=a4.x; ra[1]=a4.y; ra[2]=a4.z; ra[3]=a4.w;
      ca[0]=b4.x; ca[1]=b4.y; ca[2]=b4.z; ca[3]=b4.w;
    }
    #pragma unroll
    for (int e = 0; e < 4; e++){
      int rr = ra[e] - r0;
      if ((unsigned)rr < (unsigned)RT)
        atomicAdd(&bins[rr*NWB + (ca[e]>>3)], 1u << ((ca[e]&7)*4));
    }
  }
  __syncthreads();
  u32* dst = (side ? nHmT : nHm) + (size_t)g*KP*NWB + (size_t)r0*NWB;
  for (int k = tid; k < RT*NWB; k += 256){
    u32 v = bins[k];
    if (v) atomicAdd(dst + k, v);       // coalesced; ~30% nonzero
  }
}

// Expand phase: nibble matrix -> bf16 A-matrix + degrees. grid (66, NG, 2).
__global__ __launch_bounds__(256) void k_expand(const u32* __restrict__ nHm,
                                                const u32* __restrict__ nHmT,
                                                u16* __restrict__ AHm,
                                                u16* __restrict__ AHmT,
                                                float* __restrict__ Dinv,
                                                float* __restrict__ Binv){
  int tid = threadIdx.x;
  int g = blockIdx.y, side = blockIdx.z;
  int r0 = blockIdx.x * 16;
  const u32* src = (side ? nHmT : nHm) + (size_t)g*KP*NWB + (size_t)r0*NWB;
  u16* dst = (side ? AHmT : AHm) + (size_t)g*KP*KP + (size_t)r0*KP;
  for (int idx = tid; idx < 16*NWB; idx += 256){   // KP == NWB*8: flat map ok
    u32 v = src[idx];
    bf16x8 o;
    #pragma unroll
    for (int j = 0; j < 8; j++)
      o[j] = (short)f2bf((float)((v >> (4*j)) & 0xFu));
    *(bf16x8*)(dst + (size_t)idx*8) = o;
  }
  int r = tid >> 4, j = tid & 15;       // 16 threads per row
  u32 s = 0;
  for (int w = j; w < NWB; w += 16){
    u32 v = src[r*NWB + w];
    u32 a = (v & 0x0F0F0F0Fu) + ((v >> 4) & 0x0F0F0F0Fu);
    s += (a * 0x01010101u) >> 24;
  }
  s += __shfl_xor(s, 1); s += __shfl_xor(s, 2);
  s += __shfl_xor(s, 4); s += __shfl_xor(s, 8);
  int gr = r0 + r;
  if (j == 0 && gr < N){
    float inv = s ? 1.f/(float)s : 0.f;
    (side ? Binv : Dinv)[g*N + gr] = inv;
  }
}

// Fused GRU + attention, split-d (R13): one ticker per 256-thread block.
__global__ __launch_bounds__(256) void k_gruattn(const float* __restrict__ price,
                                                 const float* __restrict__ Wih,
                                                 const float* __restrict__ Whh,
                                                 const float* __restrict__ bih,
                                                 const float* __restrict__ bhh,
                                                 const float* __restrict__ Win,
                                                 const float* __restrict__ Wout,
                                                 const float* __restrict__ ae,
                                                 const float* __restrict__ ab,
                                                 float* __restrict__ outp){
  __shared__ float gi[T][192];
  __shared__ float sh[64];
  __shared__ float sctx[T*64];
  __shared__ float part[4][192];
  __shared__ float sx[T*F_IN];
  __shared__ float sq[64];
  __shared__ float ssc[T];
  __shared__ float sco[128];
  int tid = threadIdx.x, w = tid>>6, lane = tid&63;
  int n = blockIdx.x;
  float wr_[16], wz_[16], wn_[16];
  #pragma unroll
  for (int j = 0; j < 16; j++){
    int d = w*16 + j;
    wr_[j] = Whh[(size_t)(      lane)*64 + d];
    wz_[j] = Whh[(size_t)( 64 + lane)*64 + d];
    wn_[j] = Whh[(size_t)(128 + lane)*64 + d];
  }
  if (tid < T*F_IN) sx[tid] = price[(size_t)n*T*F_IN + tid];
  if (tid < 64) sh[tid] = 0.f;
  __syncthreads();
  for (int idx = tid; idx < T*192; idx += 256){
    int t = idx / 192, gd = idx - t*192;
    float acc = bih[gd];
    #pragma unroll
    for (int d5 = 0; d5 < F_IN; d5++)
      acc = fmaf(sx[t*F_IN + d5], Wih[gd*F_IN + d5], acc);
    gi[t][gd] = acc;
  }
  __syncthreads();
  for (int t = 0; t < T; t++){
    float pr = 0.f, pz = 0.f, pn = 0.f;
    #pragma unroll
    for (int j = 0; j < 16; j++){
      float hv = sh[w*16 + j];
      pr = fmaf(hv, wr_[j], pr);
      pz = fmaf(hv, wz_[j], pz);
      pn = fmaf(hv, wn_[j], pn);
    }
    part[w][lane] = pr; part[w][64 + lane] = pz; part[w][128 + lane] = pn;
    __syncthreads();
    if (tid < 64){
      int o = tid;
      float hr = bhh[o]       + part[0][o]     + part[1][o]     + part[2][o]     + part[3][o];
      float hz = bhh[64 + o]  + part[0][64+o]  + part[1][64+o]  + part[2][64+o]  + part[3][64+o];
      float hn = bhh[128 + o] + part[0][128+o] + part[1][128+o] + part[2][128+o] + part[3][128+o];
      float r  = 1.f/(1.f + expf(-(gi[t][o] + hr)));
      float z  = 1.f/(1.f + expf(-(gi[t][64 + o] + hz)));
      float nn = tanhf(gi[t][128 + o] + r*hn);
      float hnew = (1.f - z)*nn + z*sh[o];
      sh[o] = hnew;
      sctx[t*64 + o] = hnew;
    }
    __syncthreads();
  }
  {
    float qp = 0.f;
    #pragma unroll
    for (int j = 0; j < 16; j++)
      qp = fmaf(sh[w*16 + j], Win[(size_t)(w*16 + j)*64 + lane], qp);
    part[w][lane] = qp;
  }
  __syncthreads();
  if (tid < 64) sq[tid] = part[0][tid] + part[1][tid] + part[2][tid] + part[3][tid];
  __syncthreads();
  if (tid < T){
    float s = 0.f;
    for (int d = 0; d < 64; d++) s = fmaf(sq[d], sctx[tid*64 + d], s);
    ssc[tid] = s;
  }
  __syncthreads();
  if (tid < 64){
    int o = tid;
    float m = ssc[0];
    for (int t = 1; t < T; t++) m = fmaxf(m, ssc[t]);
    float wv[T]; float den = 0.f;
    for (int t = 0; t < T; t++){ wv[t] = expf(ssc[t] - m); den += wv[t]; }
    float aen = ae[n], abn = ab[n];
    float mixs = 0.f;
    for (int t = 0; t < T; t++){
      float wt = wv[t]/den;
      float mx = wt * sctx[t*64 + o];
      float bt = expf(-abn * (float)(T-1-t));
      mixs += fmaxf(aen*mx*bt, 0.f) + mx;
    }
    sco[o] = mixs; sco[64 + o] = sq[o];
  }
  __syncthreads();
  {
    float op = 0.f;
    #pragma unroll
    for (int j = 0; j < 32; j++)
      op = fmaf(sco[w*32 + j], Wout[(size_t)(w*32 + j)*64 + lane], op);
    part[w][lane] = op;
  }
  __syncthreads();
  if (tid < 64){
    float o = part[0][tid] + part[1][tid] + part[2][tid] + part[3][tid];
    outp[(size_t)n*H + tid] = tanhf(o);
  }
}

// xt = x @ theta in FP32 (accuracy-critical), output transposed bf16 — R13
// version (R14's 16-row variant was neutral-to-negative: 4x theta re-loads).
__global__ __launch_bounds__(256) void k_xthetaT(const float* __restrict__ x,
                                                 const float* __restrict__ theta,
                                                 int x_per_graph,
                                                 u16* __restrict__ xtT){
  __shared__ float sth[4096];
  __shared__ float sxr[64][64];
  __shared__ float syt[64][65];
  int tid = threadIdx.x, w = tid>>6, lane = tid&63;
  int g = blockIdx.y;
  int r0 = blockIdx.x*64;
  const float* xg = x + (x_per_graph ? (size_t)g*N*64 : (size_t)0);
  for (int k = tid; k < 1024; k += 256) ((float4*)sth)[k] = ((const float4*)theta)[k];
  for (int rr = w; rr < 64; rr += 4){
    int r = r0 + rr;
    sxr[rr][lane] = (r < N) ? xg[(size_t)r*64 + lane] : 0.f;
  }
  __syncthreads();
  for (int rr = w*16; rr < w*16+16; rr++){
    float acc = 0.f;
    for (int d = 0; d < 64; d++) acc = fmaf(sxr[rr][d], sth[d*64 + lane], acc);
    syt[lane][rr] = acc;
  }
  __syncthreads();
  int col = r0 + lane;
  if (col < KP){
    for (int f = w*16; f < w*16+16; f++)
      xtT[((size_t)g*64 + f)*KP + col] = f2bf(syt[f][lane]);
  }
}

// MFMA conv GEMM — R13/R10 version (verbatim). One wave = 16 rows x 16 cols.
// (R11: runtime-indexed register ring -> scratch spill, 538 us. R14: K-split
// LDS reduce -> neutral-negative. Keep explicit scalar double-buffer.)
__global__ __launch_bounds__(64) void k_gemm(const u16* __restrict__ A,
                                             const u16* __restrict__ Xt,
                                             int x_per_graph,
                                             const float* __restrict__ scale,
                                             const float* __restrict__ bias,
                                             int mode,
                                             u16* __restrict__ Yt,
                                             float* __restrict__ Yf){
  int g = blockIdx.y;
  int m0 = (blockIdx.x >> 2) * 16;
  int nt = blockIdx.x & 3;
  int lane = threadIdx.x;
  int mrow = lane & 15, quad = lane >> 4;
  const u16* Ap = A + (size_t)g*KP*KP + (size_t)(m0 + mrow)*KP + quad*8;
  const u16* Bp = Xt + (x_per_graph ? (size_t)g*64*KP : (size_t)0)
                     + (size_t)(nt*16 + mrow)*KP + quad*8;
  f32x4 acc = (f32x4){0.f,0.f,0.f,0.f};
  bf16x8 a0 = *(const bf16x8*)Ap;
  bf16x8 b0 = *(const bf16x8*)Bp;
  for (int c = 0; c < 33; c++){
    bf16x8 a1 = a0, b1 = b0;
    if (c < 32){
      a1 = *(const bf16x8*)(Ap + (c+1)*32);
      b1 = *(const bf16x8*)(Bp + (c+1)*32);
    }
    acc = __builtin_amdgcn_mfma_f32_16x16x32_bf16(a0, b0, acc, 0, 0, 0);
    a0 = a1; b0 = b1;
  }
  int mbase = m0 + quad*4;
  float sc_[4];
  #pragma unroll
  for (int r = 0; r < 4; r++){
    int m = mbase + r;
    sc_[r] = (m < N) ? scale[g*N + m] : 0.f;
  }
  if (mode == 0){
    ushort4 o;
    o.x = f2bf(acc[0]*sc_[0]);
    o.y = f2bf(acc[1]*sc_[1]);
    o.z = f2bf(acc[2]*sc_[2]);
    o.w = f2bf(acc[3]*sc_[3]);
    *(ushort4*)(Yt + ((size_t)g*64 + nt*16 + mrow)*KP + mbase) = o;
  } else {
    float bs = bias[nt*16 + mrow];
    #pragma unroll
    for (int r = 0; r < 4; r++){
      int m = mbase + r;
      if (m < N){
        float v = acc[r]*sc_[r] + bs;
        Yf[((size_t)g*N + m)*64 + nt*16 + mrow] = leakyf(v);
      }
    }
  }
}

// bz phase 1: partial sums of (x2[k+1]-x2[k]) per (k, chunk). grid (TM, BZC).
__global__ __launch_bounds__(256) void k_bz1(const float* __restrict__ x2,
                                             float* __restrict__ bpart){
  int k = blockIdx.x, ch = blockIdx.y, tid = threadIdx.x;
  int wv = tid >> 6, lane = tid & 63;
  const float4* a4 = (const float4*)(x2 + (size_t)k*NH + (size_t)ch*CHUNK);
  const float4* c4 = (const float4*)(x2 + (size_t)(k+1)*NH + (size_t)ch*CHUNK);
  float s = 0.f;
  for (int i = tid; i < CHUNK/4; i += 256){
    float4 cc = c4[i], aa = a4[i];
    s += (cc.x-aa.x)+(cc.y-aa.y)+(cc.z-aa.z)+(cc.w-aa.w);
  }
  __shared__ float red[4];
  for (int off = 32; off; off >>= 1) s += __shfl_down(s, off);
  if (lane == 0) red[wv] = s;
  __syncthreads();
  if (tid == 0) bpart[k*BZC + ch] = red[0]+red[1]+red[2]+red[3];
}

// bz phase 2: bk from bpart (deterministic), then partial z. grid (TM, BZC).
__global__ __launch_bounds__(256) void k_bz2(const float* __restrict__ x2,
                                             const float* __restrict__ bpart,
                                             const float* __restrict__ a_param,
                                             float* __restrict__ zpart){
  int k = blockIdx.x, ch = blockIdx.y, tid = threadIdx.x;
  int wv = tid >> 6, lane = tid & 63;
  __shared__ float sbk;
  if (tid == 0){
    float t = 0.f;
    for (int j = 0; j < BZC; j++) t += bpart[k*BZC + j];
    sbk = t / (float)NH;
  }
  __syncthreads();
  float bk = sbk, ap = a_param[k];
  const float4* a4 = (const float4*)(x2 + (size_t)k*NH + (size_t)ch*CHUNK);
  const float4* c4 = (const float4*)(x2 + (size_t)(k+1)*NH + (size_t)ch*CHUNK);
  float s = 0.f;
  for (int i = tid; i < CHUNK/4; i += 256){
    float4 cc = c4[i], aa = a4[i];
    float sb[4] = {cc.x-aa.x, cc.y-aa.y, cc.z-aa.z, cc.w-aa.w};
    #pragma unroll
    for (int j = 0; j < 4; j++){
      float U = 1.f/(1.f + ap*(bk - sb[j]));
      s += (U*sb[j])/U;
    }
  }
  __shared__ float red[4];
  for (int off = 32; off; off >>= 1) s += __shfl_down(s, off);
  if (lane == 0) red[wv] = s;
  __syncthreads();
  if (tid == 0) zpart[k*BZC + ch] = red[0]+red[1]+red[2]+red[3];
}

// final projection: folds zpart -> z, inline wattn softmax, dtype detect
__global__ __launch_bounds__(256) void k_final(const float* __restrict__ x2,
                                               const float* __restrict__ zpart,
                                               const float* __restrict__ w1,
                                               const float* __restrict__ w2,
                                               const float* __restrict__ Wl,
                                               const float* __restrict__ bl,
                                               const u16* __restrict__ wihRaw,
                                               void* __restrict__ outv){
  __shared__ float sz[8];
  __shared__ float sy[64];
  __shared__ float swa[8];
  int tid = threadIdx.x;
  int isf32 = detect_f32(wihRaw);
  if (tid < TM){
    float t = 0.f;
    for (int j = 0; j < BZC; j++) t += zpart[tid*BZC + j];
    sz[tid] = t;
  }
  __syncthreads();
  if (tid < 64){
    float y = 0.f;
    for (int kk = 0; kk < TM; kk++) y += w1[tid*TM + kk]*sz[kk];
    sy[tid] = leakyf(y);
  }
  __syncthreads();
  if (tid < TM){
    float v = 0.f;
    for (int d = 0; d < 64; d++) v += w2[tid*64 + d]*sy[d];
    swa[tid] = v;
  }
  __syncthreads();
  if (tid == 0){
    float m = swa[0];
    for (int t = 1; t < TM; t++) m = fmaxf(m, swa[t]);
    float den = 0.f;
    for (int t = 0; t < TM; t++){ swa[t] = expf(swa[t]-m); den += swa[t]; }
    for (int t = 0; t < TM; t++) swa[t] /= den;
  }
  __syncthreads();
  int n = blockIdx.x*256 + tid;
  if (n < N){
    float w0 = swa[0], w2v = swa[2];
    float acc = bl[0];
    for (int h = 0; h < 64; h++){
      float xg = x2[(size_t)8*NH + (size_t)n*64 + h];
      float s0 = x2[(size_t)1*NH + (size_t)n*64 + h] - x2[(size_t)0*NH + (size_t)n*64 + h];
      float s2 = x2[(size_t)3*NH + (size_t)n*64 + h] - x2[(size_t)2*NH + (size_t)n*64 + h];
      float xx = w0*s0 + w2v*s2;
      acc += xg*Wl[h] + xx*Wl[64 + h];
    }
    float r = leakyf(acc);
    if (isf32) ((float*)outv)[n] = r;
    else       ((__hip_bfloat16*)outv)[n] = __float2bfloat16(r);
  }
}

extern "C" void kernel_launch(void* const* d_in, const int* in_sizes, int n_in,
                              void* d_out, int out_size, void* d_ws, size_t ws_size,
                              hipStream_t stream) {
  const int* hypT = (const int*)d_in[1];
  const int* hyp  = (const int*)d_in[2];

  char* p = (char*)d_ws;
  auto alloc = [&](size_t bytes) -> char* {
    char* r = p; p += (bytes + 63) & ~(size_t)63; return r;
  };
  float* cv   = (float*)alloc((size_t)TOT_CVT*4);
  u32* nHm    = (u32*)  alloc((size_t)NG*KP*NWB*4);   // nibble count matrices
  u32* nHmT   = (u32*)  alloc((size_t)NG*KP*NWB*4);
  u16* AHm    = (u16*)  alloc((size_t)NG*KP*KP*2);
  u16* AHmT   = (u16*)  alloc((size_t)NG*KP*KP*2);
  float* Dinv = (float*)alloc((size_t)NG*N*4);
  float* Binv = (float*)alloc((size_t)NG*N*4);
  float* outp = (float*)alloc((size_t)N*H*4);
  float* x1   = (float*)alloc((size_t)NG*N*H*4);
  float* x2   = (float*)alloc((size_t)NG*N*H*4);
  float* bpart= (float*)alloc((size_t)TM*BZC*4);
  float* zpart= (float*)alloc((size_t)TM*BZC*4);
  u16* xtT1   = (u16*)  alloc((size_t)64*KP*2);
  u16* xtT2   = (u16*)  alloc((size_t)NG*64*KP*2);
  u16* ebufT  = (u16*)  alloc((size_t)NG*64*KP*2);

  const float* price  = cv + OFF_PRICE;
  const float* Wih    = cv + OFF_WIH;
  const float* Whh    = cv + OFF_WHH;
  const float* bih    = cv + OFF_BIH;
  const float* bhh    = cv + OFF_BHH;
  const float* Win    = cv + OFF_WIN;
  const float* Wout   = cv + OFF_WOUT;
  const float* ae     = cv + OFF_AE;
  const float* ab     = cv + OFF_AB;
  const float* theta1 = cv + OFF_TH1;
  const float* bias1  = cv + OFF_B1;
  const float* theta2 = cv + OFF_TH2;
  const float* bias2  = cv + OFF_B2;
  const float* w1     = cv + OFF_W1;
  const float* w2     = cv + OFF_W2;
  const float* a_par  = cv + OFF_APAR;
  const float* Wl     = cv + OFF_WL;
  const float* bl     = cv + OFF_BL;

  // zero the nibble matrices (contiguous)
  hipMemsetAsync(nHm, 0, (size_t)2*NG*KP*NWB*4, stream);

  CvtPtrs ps;
  ps.p[0]=d_in[0];  ps.p[1]=d_in[3];  ps.p[2]=d_in[4];  ps.p[3]=d_in[5];
  ps.p[4]=d_in[6];  ps.p[5]=d_in[7];  ps.p[6]=d_in[8];  ps.p[7]=d_in[9];
  ps.p[8]=d_in[10]; ps.p[9]=d_in[11]; ps.p[10]=d_in[12]; ps.p[11]=d_in[13];
  ps.p[12]=d_in[14]; ps.p[13]=d_in[15]; ps.p[14]=d_in[16]; ps.p[15]=d_in[17];
  ps.p[16]=d_in[18]; ps.p[17]=d_in[19];
  k_cvt<<<(TOT_CVT+255)/256, 256, 0, stream>>>(ps, cv);

  k_scan  <<<dim3(NT*PB, NG, 2), 256, 0, stream>>>(hypT, hyp, nHm, nHmT);
  k_expand<<<dim3(KP/16, NG, 2), 256, 0, stream>>>(nHm, nHmT, AHm, AHmT, Dinv, Binv);
  k_gruattn<<<N, 256, 0, stream>>>(price, Wih, Whh, bih, bhh,
                                   Win, Wout, ae, ab, outp);

  // layer 1
  k_xthetaT<<<dim3(17, 1), 256, 0, stream>>>(outp, theta1, 0, xtT1);
  k_gemm<<<dim3((KP/16)*4, NG), 64, 0, stream>>>(AHmT, xtT1, 0, Binv, nullptr, 0, ebufT, nullptr);
  k_gemm<<<dim3((KP/16)*4, NG), 64, 0, stream>>>(AHm, ebufT, 1, Dinv, bias1, 1, nullptr, x1);

  // layer 2
  k_xthetaT<<<dim3(17, NG), 256, 0, stream>>>(x1, theta2, 1, xtT2);
  k_gemm<<<dim3((KP/16)*4, NG), 64, 0, stream>>>(AHmT, xtT2, 1, Binv, nullptr, 0, ebufT, nullptr);
  k_gemm<<<dim3((KP/16)*4, NG), 64, 0, stream>>>(AHm, ebufT, 1, Dinv, bias2, 1, nullptr, x2);

  k_bz1<<<dim3(TM, BZC), 256, 0, stream>>>(x2, bpart);
  k_bz2<<<dim3(TM, BZC), 256, 0, stream>>>(x2, bpart, a_par, zpart);
  k_final<<<(N+255)/256, 256, 0, stream>>>(x2, zpart, w1, w2, Wl, bl,
                                           (const u16*)d_in[3], d_out);
}

// Round 16
// 271.599 us; speedup vs baseline: 1.1596x; 1.1596x over previous
//
#include <hip/hip_runtime.h>
#include <hip/hip_bf16.h>
#include <math.h>

#define N 1026
#define T 8
#define H 64
#define F_IN 5
#define E 1026
#define NNZ 200000
#define TM 7
#define NG 9
#define KP 1056        // padded rows/cols for conv GEMMs (66 * 16)
#define NWB 132        // nibble words per row (1056/8)
#define RT 96          // build: rows per LDS tile
#define NT 11          // 11*96 = 1056 exactly
#define NH (N*H)
#define BZC 32         // bz chunk count
#define CHUNK (NH/BZC) // 2052

#define OFF_PRICE   0
#define OFF_WIH     41040
#define OFF_WHH     42000
#define OFF_BIH     54288
#define OFF_BHH     54480
#define OFF_WIN     54672
#define OFF_WOUT    58768
#define OFF_AE      66960
#define OFF_AB      67986
#define OFF_TH1     69012
#define OFF_B1      73108
#define OFF_TH2     73172
#define OFF_B2      77268
#define OFF_W1      77332
#define OFF_W2      77780
#define OFF_APAR    78228
#define OFF_WL      78235
#define OFF_BL      78363
#define TOT_CVT     78364

typedef unsigned int u32;
typedef unsigned short u16;
typedef short bf16x8 __attribute__((ext_vector_type(8)));
typedef float f32x4 __attribute__((ext_vector_type(4)));

__device__ __forceinline__ float leakyf(float x){ return x >= 0.f ? x : 0.2f*x; }
__device__ __forceinline__ float bfbits2f(u16 u){
  union { u32 i; float f; } c; c.i = ((u32)u) << 16; return c.f;
}
__device__ __forceinline__ u16 f2bf(float f){      // round-to-nearest-even
  u32 x = __builtin_bit_cast(u32, f);
  u32 r = x + 0x7FFFu + ((x >> 16) & 1u);
  return (u16)(r >> 16);
}
__device__ __forceinline__ int detect_f32(const u16* __restrict__ w){
  int lane = threadIdx.x & 63;
  int big = 0;
  for (int k = lane; k < 960; k += 64){
    float a = fabsf(bfbits2f(w[k]));
    if (!(a < 1e3f)) big = 1;
  }
  return (__ballot(big != 0) != 0ull) ? 1 : 0;
}

struct CvtPtrs { const void* p[18]; };

__global__ __launch_bounds__(256) void k_cvt(CvtPtrs ps, float* __restrict__ dst){
  const int offs[19] = {OFF_PRICE, OFF_WIH, OFF_WHH, OFF_BIH, OFF_BHH, OFF_WIN,
                        OFF_WOUT, OFF_AE, OFF_AB, OFF_TH1, OFF_B1, OFF_TH2,
                        OFF_B2, OFF_W1, OFF_W2, OFF_APAR, OFF_WL, OFF_BL, TOT_CVT};
  int isf32 = detect_f32((const u16*)ps.p[1]);
  int i = blockIdx.x*256 + threadIdx.x;
  if (i < TOT_CVT){
    int t = 0;
    #pragma unroll
    for (int k = 1; k < 18; k++) if (i >= offs[k]) t = k;
    int j = i - offs[t];
    float v;
    if (isf32) v = ((const float*)ps.p[t])[j];
    else       v = bfbits2f(((const u16*)ps.p[t])[j]);
    dst[i] = v;
  }
}

// LDS-binned incidence build — R13 version (best measured: ~45 us, 27% occ,
// 2.1 TB/s). R15's split-scan + global-atomic flush regressed to ~70 us
// (35.9 MB atomic writeback traffic); atomics-to-HBM always lose here.
__global__ __launch_bounds__(1024) void k_build(const int* __restrict__ hypT,
                                                const int* __restrict__ hyp,
                                                u16* __restrict__ AHm,
                                                u16* __restrict__ AHmT,
                                                float* __restrict__ Dinv,
                                                float* __restrict__ Binv){
  __shared__ u32 bins[RT*NWB];          // 50,688 B
  int tid = threadIdx.x;
  int g = blockIdx.y, side = blockIdx.z;
  int r0 = blockIdx.x * RT;
  for (int k = tid; k < RT*NWB; k += 1024) bins[k] = 0;
  __syncthreads();
  const int4* np4; const int4* ep4;
  if (g < 8){ const int* np_ = hypT + (size_t)g*2*NNZ;
              np4 = (const int4*)np_; ep4 = (const int4*)(np_ + NNZ); }
  else      { np4 = (const int4*)hyp; ep4 = (const int4*)(hyp + NNZ); }
  #pragma unroll 4
  for (int i = tid; i < NNZ/4; i += 1024){
    int4 a4 = np4[i], b4 = ep4[i];
    int ra[4], ca[4];
    if (side){
      ra[0]=b4.x; ra[1]=b4.y; ra[2]=b4.z; ra[3]=b4.w;
      ca[0]=a4.x; ca[1]=a4.y; ca[2]=a4.z; ca[3]=a4.w;
    } else {
      ra[0]=a4.x; ra[1]=a4.y; ra[2]=a4.z; ra[3]=a4.w;
      ca[0]=b4.x; ca[1]=b4.y; ca[2]=b4.z; ca[3]=b4.w;
    }
    #pragma unroll
    for (int e = 0; e < 4; e++){
      int rr = ra[e] - r0;
      if ((unsigned)rr < (unsigned)RT)
        atomicAdd(&bins[rr*NWB + (ca[e]>>3)], 1u << ((ca[e]&7)*4));
    }
  }
  __syncthreads();
  {
    int r = tid >> 3, j = tid & 7;
    if (r < RT){
      u32 s = 0;
      for (int w = j; w < NWB; w += 8){
        u32 v = bins[r*NWB + w];
        u32 a = (v & 0x0F0F0F0Fu) + ((v >> 4) & 0x0F0F0F0Fu);
        s += (a * 0x01010101u) >> 24;
      }
      s += __shfl_xor(s, 1); s += __shfl_xor(s, 2); s += __shfl_xor(s, 4);
      int gr = r0 + r;
      if (j == 0 && gr < N){
        float inv = s ? 1.f/(float)s : 0.f;
        (side ? Binv : Dinv)[g*N + gr] = inv;
      }
    }
  }
  u16* dst = (side ? AHmT : AHm) + (size_t)g*KP*KP;
  for (int idx = tid; idx < RT*NWB; idx += 1024){
    int rr = idx / NWB, w = idx - rr*NWB;
    u32 v = bins[rr*NWB + w];
    bf16x8 o;
    #pragma unroll
    for (int j = 0; j < 8; j++)
      o[j] = (short)f2bf((float)((v >> (4*j)) & 0xFu));
    *(bf16x8*)(dst + (size_t)(r0 + rr)*KP + w*8) = o;
  }
}

// Fused GRU + attention, split-d (R13): one ticker per 256-thread block.
__global__ __launch_bounds__(256) void k_gruattn(const float* __restrict__ price,
                                                 const float* __restrict__ Wih,
                                                 const float* __restrict__ Whh,
                                                 const float* __restrict__ bih,
                                                 const float* __restrict__ bhh,
                                                 const float* __restrict__ Win,
                                                 const float* __restrict__ Wout,
                                                 const float* __restrict__ ae,
                                                 const float* __restrict__ ab,
                                                 float* __restrict__ outp){
  __shared__ float gi[T][192];
  __shared__ float sh[64];
  __shared__ float sctx[T*64];
  __shared__ float part[4][192];
  __shared__ float sx[T*F_IN];
  __shared__ float sq[64];
  __shared__ float ssc[T];
  __shared__ float sco[128];
  int tid = threadIdx.x, w = tid>>6, lane = tid&63;
  int n = blockIdx.x;
  float wr_[16], wz_[16], wn_[16];
  #pragma unroll
  for (int j = 0; j < 16; j++){
    int d = w*16 + j;
    wr_[j] = Whh[(size_t)(      lane)*64 + d];
    wz_[j] = Whh[(size_t)( 64 + lane)*64 + d];
    wn_[j] = Whh[(size_t)(128 + lane)*64 + d];
  }
  if (tid < T*F_IN) sx[tid] = price[(size_t)n*T*F_IN + tid];
  if (tid < 64) sh[tid] = 0.f;
  __syncthreads();
  for (int idx = tid; idx < T*192; idx += 256){
    int t = idx / 192, gd = idx - t*192;
    float acc = bih[gd];
    #pragma unroll
    for (int d5 = 0; d5 < F_IN; d5++)
      acc = fmaf(sx[t*F_IN + d5], Wih[gd*F_IN + d5], acc);
    gi[t][gd] = acc;
  }
  __syncthreads();
  for (int t = 0; t < T; t++){
    float pr = 0.f, pz = 0.f, pn = 0.f;
    #pragma unroll
    for (int j = 0; j < 16; j++){
      float hv = sh[w*16 + j];
      pr = fmaf(hv, wr_[j], pr);
      pz = fmaf(hv, wz_[j], pz);
      pn = fmaf(hv, wn_[j], pn);
    }
    part[w][lane] = pr; part[w][64 + lane] = pz; part[w][128 + lane] = pn;
    __syncthreads();
    if (tid < 64){
      int o = tid;
      float hr = bhh[o]       + part[0][o]     + part[1][o]     + part[2][o]     + part[3][o];
      float hz = bhh[64 + o]  + part[0][64+o]  + part[1][64+o]  + part[2][64+o]  + part[3][64+o];
      float hn = bhh[128 + o] + part[0][128+o] + part[1][128+o] + part[2][128+o] + part[3][128+o];
      float r  = 1.f/(1.f + expf(-(gi[t][o] + hr)));
      float z  = 1.f/(1.f + expf(-(gi[t][64 + o] + hz)));
      float nn = tanhf(gi[t][128 + o] + r*hn);
      float hnew = (1.f - z)*nn + z*sh[o];
      sh[o] = hnew;
      sctx[t*64 + o] = hnew;
    }
    __syncthreads();
  }
  {
    float qp = 0.f;
    #pragma unroll
    for (int j = 0; j < 16; j++)
      qp = fmaf(sh[w*16 + j], Win[(size_t)(w*16 + j)*64 + lane], qp);
    part[w][lane] = qp;
  }
  __syncthreads();
  if (tid < 64) sq[tid] = part[0][tid] + part[1][tid] + part[2][tid] + part[3][tid];
  __syncthreads();
  if (tid < T){
    float s = 0.f;
    for (int d = 0; d < 64; d++) s = fmaf(sq[d], sctx[tid*64 + d], s);
    ssc[tid] = s;
  }
  __syncthreads();
  if (tid < 64){
    int o = tid;
    float m = ssc[0];
    for (int t = 1; t < T; t++) m = fmaxf(m, ssc[t]);
    float wv[T]; float den = 0.f;
    for (int t = 0; t < T; t++){ wv[t] = expf(ssc[t] - m); den += wv[t]; }
    float aen = ae[n], abn = ab[n];
    float mixs = 0.f;
    for (int t = 0; t < T; t++){
      float wt = wv[t]/den;
      float mx = wt * sctx[t*64 + o];
      float bt = expf(-abn * (float)(T-1-t));
      mixs += fmaxf(aen*mx*bt, 0.f) + mx;
    }
    sco[o] = mixs; sco[64 + o] = sq[o];
  }
  __syncthreads();
  {
    float op = 0.f;
    #pragma unroll
    for (int j = 0; j < 32; j++)
      op = fmaf(sco[w*32 + j], Wout[(size_t)(w*32 + j)*64 + lane], op);
    part[w][lane] = op;
  }
  __syncthreads();
  if (tid < 64){
    float o = part[0][tid] + part[1][tid] + part[2][tid] + part[3][tid];
    outp[(size_t)n*H + tid] = tanhf(o);
  }
}

// xt = x @ theta in FP32 (accuracy-critical; MFMA input-rounding regressed
// absmax 6x in R6), output transposed bf16 xtT[g][f][k], pads -> 0.
__global__ __launch_bounds__(256) void k_xthetaT(const float* __restrict__ x,
                                                 const float* __restrict__ theta,
                                                 int x_per_graph,
                                                 u16* __restrict__ xtT){
  __shared__ float sth[4096];
  __shared__ float sxr[64][64];
  __shared__ float syt[64][65];
  int tid = threadIdx.x, w = tid>>6, lane = tid&63;
  int g = blockIdx.y;
  int r0 = blockIdx.x*64;
  const float* xg = x + (x_per_graph ? (size_t)g*N*64 : (size_t)0);
  for (int k = tid; k < 1024; k += 256) ((float4*)sth)[k] = ((const float4*)theta)[k];
  for (int rr = w; rr < 64; rr += 4){
    int r = r0 + rr;
    sxr[rr][lane] = (r < N) ? xg[(size_t)r*64 + lane] : 0.f;
  }
  __syncthreads();
  for (int rr = w*16; rr < w*16+16; rr++){
    float acc = 0.f;
    for (int d = 0; d < 64; d++) acc = fmaf(sxr[rr][d], sth[d*64 + lane], acc);
    syt[lane][rr] = acc;
  }
  __syncthreads();
  int col = r0 + lane;
  if (col < KP){
    for (int f = w*16; f < w*16+16; f++)
      xtT[((size_t)g*64 + f)*KP + col] = f2bf(syt[f][lane]);
  }
}

// MFMA conv GEMM — R13/R10 version. One wave = 16 rows x 16 cols.
// (R11: runtime-indexed register ring -> scratch spill. R14: K-split LDS
// reduce -> neutral-negative. Explicit scalar double-buffer is the winner.)
__global__ __launch_bounds__(64) void k_gemm(const u16* __restrict__ A,
                                             const u16* __restrict__ Xt,
                                             int x_per_graph,
                                             const float* __restrict__ scale,
                                             const float* __restrict__ bias,
                                             int mode,
                                             u16* __restrict__ Yt,
                                             float* __restrict__ Yf){
  int g = blockIdx.y;
  int m0 = (blockIdx.x >> 2) * 16;
  int nt = blockIdx.x & 3;
  int lane = threadIdx.x;
  int mrow = lane & 15, quad = lane >> 4;
  const u16* Ap = A + (size_t)g*KP*KP + (size_t)(m0 + mrow)*KP + quad*8;
  const u16* Bp = Xt + (x_per_graph ? (size_t)g*64*KP : (size_t)0)
                     + (size_t)(nt*16 + mrow)*KP + quad*8;
  f32x4 acc = (f32x4){0.f,0.f,0.f,0.f};
  bf16x8 a0 = *(const bf16x8*)Ap;
  bf16x8 b0 = *(const bf16x8*)Bp;
  for (int c = 0; c < 33; c++){
    bf16x8 a1 = a0, b1 = b0;
    if (c < 32){
      a1 = *(const bf16x8*)(Ap + (c+1)*32);
      b1 = *(const bf16x8*)(Bp + (c+1)*32);
    }
    acc = __builtin_amdgcn_mfma_f32_16x16x32_bf16(a0, b0, acc, 0, 0, 0);
    a0 = a1; b0 = b1;
  }
  int mbase = m0 + quad*4;
  float sc_[4];
  #pragma unroll
  for (int r = 0; r < 4; r++){
    int m = mbase + r;
    sc_[r] = (m < N) ? scale[g*N + m] : 0.f;
  }
  if (mode == 0){
    ushort4 o;
    o.x = f2bf(acc[0]*sc_[0]);
    o.y = f2bf(acc[1]*sc_[1]);
    o.z = f2bf(acc[2]*sc_[2]);
    o.w = f2bf(acc[3]*sc_[3]);
    *(ushort4*)(Yt + ((size_t)g*64 + nt*16 + mrow)*KP + mbase) = o;
  } else {
    float bs = bias[nt*16 + mrow];
    #pragma unroll
    for (int r = 0; r < 4; r++){
      int m = mbase + r;
      if (m < N){
        float v = acc[r]*sc_[r] + bs;
        Yf[((size_t)g*N + m)*64 + nt*16 + mrow] = leakyf(v);
      }
    }
  }
}

// bz phase 1: partial sums of (x2[k+1]-x2[k]) per (k, chunk). grid (TM, BZC).
__global__ __launch_bounds__(256) void k_bz1(const float* __restrict__ x2,
                                             float* __restrict__ bpart){
  int k = blockIdx.x, ch = blockIdx.y, tid = threadIdx.x;
  int wv = tid >> 6, lane = tid & 63;
  const float4* a4 = (const float4*)(x2 + (size_t)k*NH + (size_t)ch*CHUNK);
  const float4* c4 = (const float4*)(x2 + (size_t)(k+1)*NH + (size_t)ch*CHUNK);
  float s = 0.f;
  for (int i = tid; i < CHUNK/4; i += 256){
    float4 cc = c4[i], aa = a4[i];
    s += (cc.x-aa.x)+(cc.y-aa.y)+(cc.z-aa.z)+(cc.w-aa.w);
  }
  __shared__ float red[4];
  for (int off = 32; off; off >>= 1) s += __shfl_down(s, off);
  if (lane == 0) red[wv] = s;
  __syncthreads();
  if (tid == 0) bpart[k*BZC + ch] = red[0]+red[1]+red[2]+red[3];
}

// bz phase 2: bk from bpart (deterministic), then partial z. grid (TM, BZC).
__global__ __launch_bounds__(256) void k_bz2(const float* __restrict__ x2,
                                             const float* __restrict__ bpart,
                                             const float* __restrict__ a_param,
                                             float* __restrict__ zpart){
  int k = blockIdx.x, ch = blockIdx.y, tid = threadIdx.x;
  int wv = tid >> 6, lane = tid & 63;
  __shared__ float sbk;
  if (tid == 0){
    float t = 0.f;
    for (int j = 0; j < BZC; j++) t += bpart[k*BZC + j];
    sbk = t / (float)NH;
  }
  __syncthreads();
  float bk = sbk, ap = a_param[k];
  const float4* a4 = (const float4*)(x2 + (size_t)k*NH + (size_t)ch*CHUNK);
  const float4* c4 = (const float4*)(x2 + (size_t)(k+1)*NH + (size_t)ch*CHUNK);
  float s = 0.f;
  for (int i = tid; i < CHUNK/4; i += 256){
    float4 cc = c4[i], aa = a4[i];
    float sb[4] = {cc.x-aa.x, cc.y-aa.y, cc.z-aa.z, cc.w-aa.w};
    #pragma unroll
    for (int j = 0; j < 4; j++){
      float U = 1.f/(1.f + ap*(bk - sb[j]));
      s += (U*sb[j])/U;
    }
  }
  __shared__ float red[4];
  for (int off = 32; off; off >>= 1) s += __shfl_down(s, off);
  if (lane == 0) red[wv] = s;
  __syncthreads();
  if (tid == 0) zpart[k*BZC + ch] = red[0]+red[1]+red[2]+red[3];
}

// final projection: folds zpart -> z, inline wattn softmax, dtype detect
__global__ __launch_bounds__(256) void k_final(const float* __restrict__ x2,
                                               const float* __restrict__ zpart,
                                               const float* __restrict__ w1,
                                               const float* __restrict__ w2,
                                               const float* __restrict__ Wl,
                                               const float* __restrict__ bl,
                                               const u16* __restrict__ wihRaw,
                                               void* __restrict__ outv){
  __shared__ float sz[8];
  __shared__ float sy[64];
  __shared__ float swa[8];
  int tid = threadIdx.x;
  int isf32 = detect_f32(wihRaw);
  if (tid < TM){
    float t = 0.f;
    for (int j = 0; j < BZC; j++) t += zpart[tid*BZC + j];
    sz[tid] = t;
  }
  __syncthreads();
  if (tid < 64){
    float y = 0.f;
    for (int kk = 0; kk < TM; kk++) y += w1[tid*TM + kk]*sz[kk];
    sy[tid] = leakyf(y);
  }
  __syncthreads();
  if (tid < TM){
    float v = 0.f;
    for (int d = 0; d < 64; d++) v += w2[tid*64 + d]*sy[d];
    swa[tid] = v;
  }
  __syncthreads();
  if (tid == 0){
    float m = swa[0];
    for (int t = 1; t < TM; t++) m = fmaxf(m, swa[t]);
    float den = 0.f;
    for (int t = 0; t < TM; t++){ swa[t] = expf(swa[t]-m); den += swa[t]; }
    for (int t = 0; t < TM; t++) swa[t] /= den;
  }
  __syncthreads();
  int n = blockIdx.x*256 + tid;
  if (n < N){
    float w0 = swa[0], w2v = swa[2];
    float acc = bl[0];
    for (int h = 0; h < 64; h++){
      float xg = x2[(size_t)8*NH + (size_t)n*64 + h];
      float s0 = x2[(size_t)1*NH + (size_t)n*64 + h] - x2[(size_t)0*NH + (size_t)n*64 + h];
      float s2 = x2[(size_t)3*NH + (size_t)n*64 + h] - x2[(size_t)2*NH + (size_t)n*64 + h];
      float xx = w0*s0 + w2v*s2;
      acc += xg*Wl[h] + xx*Wl[64 + h];
    }
    float r = leakyf(acc);
    if (isf32) ((float*)outv)[n] = r;
    else       ((__hip_bfloat16*)outv)[n] = __float2bfloat16(r);
  }
}

extern "C" void kernel_launch(void* const* d_in, const int* in_sizes, int n_in,
                              void* d_out, int out_size, void* d_ws, size_t ws_size,
                              hipStream_t stream) {
  const int* hypT = (const int*)d_in[1];
  const int* hyp  = (const int*)d_in[2];

  char* p = (char*)d_ws;
  auto alloc = [&](size_t bytes) -> char* {
    char* r = p; p += (bytes + 63) & ~(size_t)63; return r;
  };
  float* cv   = (float*)alloc((size_t)TOT_CVT*4);
  u16* AHm    = (u16*)  alloc((size_t)NG*KP*KP*2);
  u16* AHmT   = (u16*)  alloc((size_t)NG*KP*KP*2);
  float* Dinv = (float*)alloc((size_t)NG*N*4);
  float* Binv = (float*)alloc((size_t)NG*N*4);
  float* outp = (float*)alloc((size_t)N*H*4);
  float* x1   = (float*)alloc((size_t)NG*N*H*4);
  float* x2   = (float*)alloc((size_t)NG*N*H*4);
  float* bpart= (float*)alloc((size_t)TM*BZC*4);
  float* zpart= (float*)alloc((size_t)TM*BZC*4);
  u16* xtT1   = (u16*)  alloc((size_t)64*KP*2);
  u16* xtT2   = (u16*)  alloc((size_t)NG*64*KP*2);
  u16* ebufT  = (u16*)  alloc((size_t)NG*64*KP*2);

  const float* price  = cv + OFF_PRICE;
  const float* Wih    = cv + OFF_WIH;
  const float* Whh    = cv + OFF_WHH;
  const float* bih    = cv + OFF_BIH;
  const float* bhh    = cv + OFF_BHH;
  const float* Win    = cv + OFF_WIN;
  const float* Wout   = cv + OFF_WOUT;
  const float* ae     = cv + OFF_AE;
  const float* ab     = cv + OFF_AB;
  const float* theta1 = cv + OFF_TH1;
  const float* bias1  = cv + OFF_B1;
  const float* theta2 = cv + OFF_TH2;
  const float* bias2  = cv + OFF_B2;
  const float* w1     = cv + OFF_W1;
  const float* w2     = cv + OFF_W2;
  const float* a_par  = cv + OFF_APAR;
  const float* Wl     = cv + OFF_WL;
  const float* bl     = cv + OFF_BL;

  CvtPtrs ps;
  ps.p[0]=d_in[0];  ps.p[1]=d_in[3];  ps.p[2]=d_in[4];  ps.p[3]=d_in[5];
  ps.p[4]=d_in[6];  ps.p[5]=d_in[7];  ps.p[6]=d_in[8];  ps.p[7]=d_in[9];
  ps.p[8]=d_in[10]; ps.p[9]=d_in[11]; ps.p[10]=d_in[12]; ps.p[11]=d_in[13];
  ps.p[12]=d_in[14]; ps.p[13]=d_in[15]; ps.p[14]=d_in[16]; ps.p[15]=d_in[17];
  ps.p[16]=d_in[18]; ps.p[17]=d_in[19];
  k_cvt<<<(TOT_CVT+255)/256, 256, 0, stream>>>(ps, cv);

  k_build<<<dim3(NT, NG, 2), 1024, 0, stream>>>(hypT, hyp, AHm, AHmT, Dinv, Binv);
  k_gruattn<<<N, 256, 0, stream>>>(price, Wih, Whh, bih, bhh,
                                   Win, Wout, ae, ab, outp);

  // layer 1
  k_xthetaT<<<dim3(17, 1), 256, 0, stream>>>(outp, theta1, 0, xtT1);
  k_gemm<<<dim3((KP/16)*4, NG), 64, 0, stream>>>(AHmT, xtT1, 0, Binv, nullptr, 0, ebufT, nullptr);
  k_gemm<<<dim3((KP/16)*4, NG), 64, 0, stream>>>(AHm, ebufT, 1, Dinv, bias1, 1, nullptr, x1);

  // layer 2
  k_xthetaT<<<dim3(17, NG), 256, 0, stream>>>(x1, theta2, 1, xtT2);
  k_gemm<<<dim3((KP/16)*4, NG), 64, 0, stream>>>(AHmT, xtT2, 1, Binv, nullptr, 0, ebufT, nullptr);
  k_gemm<<<dim3((KP/16)*4, NG), 64, 0, stream>>>(AHm, ebufT, 1, Dinv, bias2, 1, nullptr, x2);

  k_bz1<<<dim3(TM, BZC), 256, 0, stream>>>(x2, bpart);
  k_bz2<<<dim3(TM, BZC), 256, 0, stream>>>(x2, bpart, a_par, zpart);
  k_final<<<(N+255)/256, 256, 0, stream>>>(x2, zpart, w1, w2, Wl, bl,
                                           (const u16*)d_in[3], d_out);
}